// Round 1
// baseline (10157.048 us; speedup 1.0000x reference)
//
#include <hip/hip_runtime.h>

#define N_PTS   16384
#define M_PTS   4096
#define NS      16
#define C_IN    64
#define C_FEAT  67      // 3 + 64
#define C_OUT   128
#define QPB     8
#define GEMM_BLOCKS (M_PTS / QPB)   // 512
#define N_O_POS (M_PTS*3 + M_PTS*C_OUT)   // 536576

// ---------------------------------------------------------------------------
// FPS: single workgroup, 1024 threads x 16 points each, exact np semantics
// (no FMA contraction, first-index argmax tie-break).
// ---------------------------------------------------------------------------
__global__ __launch_bounds__(1024)
void fps_kernel(const float* __restrict__ p, int* __restrict__ fidx)
{
#pragma clang fp contract(off)
    const int t    = threadIdx.x;
    const int lane = t & 63;
    const int wid  = t >> 6;

    float px[16], py[16], pz[16], dist[16];
#pragma unroll
    for (int k = 0; k < 16; ++k) {
        const int i = t + (k << 10);
        px[k] = p[3*i+0]; py[k] = p[3*i+1]; pz[k] = p[3*i+2];
        dist[k] = 1e10f;
    }

    __shared__ float swv[16];
    __shared__ int   swi[16];
    __shared__ float sq[4];

    if (t == 0) fidx[0] = 0;
    float qx = p[0], qy = p[1], qz = p[2];   // uniform read, first iter only

    for (int it = 1; it < M_PTS; ++it) {
        float bv = -1.0f; int bi = 0x7fffffff;
#pragma unroll
        for (int k = 0; k < 16; ++k) {
            const float dx = px[k] - qx;
            const float dy = py[k] - qy;
            const float dz = pz[k] - qz;
            float d = dx*dx + dy*dy;   // exact np order, no fma
            d = d + dz*dz;
            const float nd = fminf(dist[k], d);
            dist[k] = nd;
            const bool take = nd > bv;          // ascending index => first max kept
            bv = take ? nd : bv;
            bi = take ? (t + (k << 10)) : bi;
        }
        // wave64 reduce (val,idx), smaller idx wins ties
#pragma unroll
        for (int off = 1; off < 64; off <<= 1) {
            const float ov = __shfl_xor(bv, off, 64);
            const int   oi = __shfl_xor(bi, off, 64);
            const bool take = (ov > bv) || (ov == bv && oi < bi);
            bv = take ? ov : bv;  bi = take ? oi : bi;
        }
        if (lane == 0) { swv[wid] = bv; swi[wid] = bi; }
        __syncthreads();
        // every wave redundantly reduces the 16 wave results -> all lanes get winner
        float v2 = swv[lane & 15]; int i2 = swi[lane & 15];
#pragma unroll
        for (int off = 1; off < 16; off <<= 1) {
            const float ov = __shfl_xor(v2, off, 64);
            const int   oi = __shfl_xor(i2, off, 64);
            const bool take = (ov > v2) || (ov == v2 && oi < i2);
            v2 = take ? ov : v2;  i2 = take ? oi : i2;
        }
        const int cur = i2;
        if (t == (cur & 1023)) {
            const int k = cur >> 10;
            float ax = 0.f, ay = 0.f, az = 0.f;
#pragma unroll
            for (int k2 = 0; k2 < 16; ++k2) {
                if (k2 == k) { ax = px[k2]; ay = py[k2]; az = pz[k2]; }
            }
            sq[0] = ax; sq[1] = ay; sq[2] = az;
            fidx[it] = cur;
        }
        __syncthreads();
        qx = sq[0]; qy = sq[1]; qz = sq[2];
    }
}

// ---------------------------------------------------------------------------
// kNN: one wave per query; lane scans 256 coalesced candidates keeping an
// unsorted register top-16; 16-round shuffle extract-min merge.
// ---------------------------------------------------------------------------
__global__ __launch_bounds__(256)
void knn_kernel(const float* __restrict__ p, const int* __restrict__ fidx,
                int* __restrict__ knn_out, float* __restrict__ out_np)
{
    const int lane = threadIdx.x & 63;
    const int wid  = threadIdx.x >> 6;
    const int m    = blockIdx.x * 4 + wid;

    const int iq = fidx[m];
    const float qx = p[3*iq+0], qy = p[3*iq+1], qz = p[3*iq+2];
    if (lane == 0) { out_np[m*3+0] = qx; out_np[m*3+1] = qy; out_np[m*3+2] = qz; }

    float d16[16]; int i16[16];
#pragma unroll
    for (int jj = 0; jj < 16; ++jj) {
        const int j = jj*64 + lane;
        const float dx = p[3*j+0]-qx, dy = p[3*j+1]-qy, dz = p[3*j+2]-qz;
        d16[jj] = fmaf(dx, dx, fmaf(dy, dy, dz*dz));
        i16[jj] = j;
    }
    float wv = d16[0];
#pragma unroll
    for (int k = 1; k < 16; ++k) wv = fmaxf(wv, d16[k]);

    for (int jj = 16; jj < 256; ++jj) {
        const int j = jj*64 + lane;
        const float dx = p[3*j+0]-qx, dy = p[3*j+1]-qy, dz = p[3*j+2]-qz;
        const float d = fmaf(dx, dx, fmaf(dy, dy, dz*dz));
        if (d < wv) {
            bool done = false;
#pragma unroll
            for (int k = 0; k < 16; ++k) {
                const bool is = (!done) && (d16[k] == wv);
                d16[k] = is ? d : d16[k];
                i16[k] = is ? j : i16[k];
                done = done || is;
            }
            wv = d16[0];
#pragma unroll
            for (int k = 1; k < 16; ++k) wv = fmaxf(wv, d16[k]);
        }
    }

    // lane-local min (val, idx)
    float lmv; int lmi;
    {
        lmv = d16[0]; lmi = i16[0];
#pragma unroll
        for (int k = 1; k < 16; ++k) {
            const bool tk = (d16[k] < lmv) || (d16[k] == lmv && i16[k] < lmi);
            lmv = tk ? d16[k] : lmv;  lmi = tk ? i16[k] : lmi;
        }
    }
    int mykn = 0;
    for (int r = 0; r < 16; ++r) {
        float v = lmv; int ii = lmi;
#pragma unroll
        for (int off = 1; off < 64; off <<= 1) {
            const float ov = __shfl_xor(v, off, 64);
            const int   oi = __shfl_xor(ii, off, 64);
            const bool tk = (ov < v) || (ov == v && oi < ii);
            v = tk ? ov : v;  ii = tk ? oi : ii;
        }
        if (lane == r) mykn = ii;
        if (lmi == ii) {            // winner lane (point indices are globally unique)
#pragma unroll
            for (int k = 0; k < 16; ++k)
                d16[k] = (i16[k] == ii) ? 3.4e38f : d16[k];
            lmv = d16[0]; lmi = i16[0];
#pragma unroll
            for (int k = 1; k < 16; ++k) {
                const bool tk = (d16[k] < lmv) || (d16[k] == lmv && i16[k] < lmi);
                lmv = tk ? d16[k] : lmv;  lmi = tk ? i16[k] : lmi;
            }
        }
    }
    if (lane < 16) knn_out[m*16 + lane] = mykn;
}

// ---------------------------------------------------------------------------
// Gather + Linear (+stats | +BN/ReLU/maxpool).  PHASE 0: partial sums.
// PHASE 1: recompute y, apply scale/shift, relu, max over s, write out.
// ---------------------------------------------------------------------------
template <int PHASE>
__global__ __launch_bounds__(256)
void gemm_kernel(const float* __restrict__ p, const float* __restrict__ x,
                 const int* __restrict__ knn, const float* __restrict__ W,
                 const float* __restrict__ np_buf, float* __restrict__ part,
                 const float* __restrict__ scsh, float* __restrict__ out_y)
{
    __shared__ float w_lds[C_OUT * C_FEAT];
    __shared__ float feats[NS * 68];         // rows padded to 68 (16B-aligned)
    __shared__ float tmp[512];

    const int tid = threadIdx.x;
    for (int e = tid; e < C_OUT * C_FEAT; e += 256) w_lds[e] = W[e];
    __syncthreads();

    const int o  = tid & 127;
    const int s0 = (tid >> 7) * 8;
    float wreg[C_FEAT];
#pragma unroll
    for (int c = 0; c < C_FEAT; ++c) wreg[c] = w_lds[o * C_FEAT + c];

    float sc = 0.f, sh = 0.f;
    if (PHASE == 1) { sc = scsh[o]; sh = scsh[128 + o]; }

    float lsum = 0.f, lsq = 0.f;

    for (int ml = 0; ml < QPB; ++ml) {
        const int m = blockIdx.x * QPB + ml;
        __syncthreads();
        for (int e = tid; e < NS * C_FEAT; e += 256) {
            const int s = e / C_FEAT;
            const int c = e - s * C_FEAT;
            const int j = knn[m * NS + s];
            float v;
            if (c < 3) v = p[3*j + c] - np_buf[m*3 + c];
            else       v = x[j * C_IN + (c - 3)];
            feats[s * 68 + c] = v;
        }
        __syncthreads();

        float mx = 0.0f;   // relu output >= 0, so 0 is a valid identity
#pragma unroll
        for (int s8 = 0; s8 < 8; ++s8) {
            const int s = s0 + s8;
            const float4* fr = (const float4*)&feats[s * 68];
            float a = 0.f;
#pragma unroll
            for (int c4 = 0; c4 < 16; ++c4) {
                const float4 f = fr[c4];
                a = fmaf(f.x, wreg[c4*4+0], a);
                a = fmaf(f.y, wreg[c4*4+1], a);
                a = fmaf(f.z, wreg[c4*4+2], a);
                a = fmaf(f.w, wreg[c4*4+3], a);
            }
            a = fmaf(feats[s*68+64], wreg[64], a);
            a = fmaf(feats[s*68+65], wreg[65], a);
            a = fmaf(feats[s*68+66], wreg[66], a);
            if (PHASE == 0) { lsum += a; lsq = fmaf(a, a, lsq); }
            else {
                float v = fmaf(a, sc, sh);
                v = fmaxf(v, 0.f);
                mx = fmaxf(mx, v);
            }
        }
        if (PHASE == 1) {
            tmp[tid] = mx;
            __syncthreads();
            if (tid < 128) out_y[m * C_OUT + o] = fmaxf(tmp[tid], tmp[tid + 128]);
        }
    }

    if (PHASE == 0) {
        tmp[tid] = lsum; tmp[256 + tid] = lsq;
        __syncthreads();
        if (tid < 128) {
            part[blockIdx.x * 256 + o]       = tmp[tid] + tmp[tid + 128];
            part[blockIdx.x * 256 + 128 + o] = tmp[256 + tid] + tmp[256 + tid + 128];
        }
    }
}

// ---------------------------------------------------------------------------
// Reduce partials -> BN scale/shift; also writes n_o.
// ---------------------------------------------------------------------------
__global__ __launch_bounds__(128)
void stats_kernel(const float* __restrict__ part, const float* __restrict__ gamma,
                  const float* __restrict__ beta, float* __restrict__ scsh,
                  float* __restrict__ out)
{
    const int o = threadIdx.x;
    float s = 0.f, s2 = 0.f;
    for (int b = 0; b < GEMM_BLOCKS; ++b) {
        s  += part[b * 256 + o];
        s2 += part[b * 256 + 128 + o];
    }
    const float inv  = 1.0f / 65536.0f;
    const float mean = s * inv;
    const float var  = fmaf(s2, inv, -mean * mean);
    const float sc   = gamma[o] * rsqrtf(var + 1e-5f);
    const float sh   = fmaf(-mean, sc, beta[o]);
    scsh[o] = sc; scsh[128 + o] = sh;
    if (o == 0) out[N_O_POS] = 4096.0f;   // n_o = N // STRIDE
}

// ---------------------------------------------------------------------------
extern "C" void kernel_launch(void* const* d_in, const int* in_sizes, int n_in,
                              void* d_out, int out_size, void* d_ws, size_t ws_size,
                              hipStream_t stream)
{
    const float* p     = (const float*)d_in[0];
    const float* x     = (const float*)d_in[1];
    const float* W     = (const float*)d_in[3];
    const float* gamma = (const float*)d_in[4];
    const float* beta  = (const float*)d_in[5];
    float* out = (float*)d_out;

    int*   fidx = (int*)d_ws;                       // 4096
    int*   knn  = fidx + M_PTS;                     // 4096*16
    float* part = (float*)(knn + M_PTS * NS);       // 512*256
    float* scsh = part + GEMM_BLOCKS * 256;         // 256

    float* out_np = out;                            // (M,3)
    float* out_y  = out + M_PTS * 3;                // (M,128)

    fps_kernel<<<dim3(1), dim3(1024), 0, stream>>>(p, fidx);
    knn_kernel<<<dim3(M_PTS / 4), dim3(256), 0, stream>>>(p, fidx, knn, out_np);
    gemm_kernel<0><<<dim3(GEMM_BLOCKS), dim3(256), 0, stream>>>(
        p, x, knn, W, out_np, part, scsh, out_y);
    stats_kernel<<<dim3(1), dim3(128), 0, stream>>>(part, gamma, beta, scsh, out);
    gemm_kernel<1><<<dim3(GEMM_BLOCKS), dim3(256), 0, stream>>>(
        p, x, knn, W, out_np, part, scsh, out_y);
}